// Round 4
// baseline (1401.458 us; speedup 1.0000x reference)
//
#include <hip/hip_runtime.h>
#include <stdint.h>

// LSTM cell: B=16384, IN=1024, H=1024, fp32 in/out.
// Split-bf16 3-term GEMM expressed as one K'=6144 bf16 GEMM:
//   A' = [Ah | Al | Ah], B' = [Wh | Wh | Wl]  (segment-select, not materialized)
// 256x256 tile, BK=32, ring-4 LDS (128 KiB), counted vmcnt(8), setprio,
// gate-interleaved weights (n=4h+g), fused activation epilogue.

#define BB 16384
#define KK 2048   // physical K per segment
#define HH 1024
#define NN 4096   // 4 gates interleaved
#define KSTEPS 192  // K' = 6144, BK = 32

typedef float  f32x4  __attribute__((ext_vector_type(4)));
typedef __bf16 bf16x8 __attribute__((ext_vector_type(8)));
typedef short  s16x8  __attribute__((ext_vector_type(8)));

__device__ __forceinline__ ushort f2bf(float f) {
  uint32_t x = __float_as_uint(f);
  x += 0x7fffu + ((x >> 16) & 1u);
  return (ushort)(x >> 16);
}
__device__ __forceinline__ float bf2f(ushort h) {
  return __uint_as_float(((uint32_t)h) << 16);
}

__device__ __forceinline__ void split8(const float* __restrict__ src, s16x8* hi, s16x8* lo) {
  float4 v0 = *(const float4*)src;
  float4 v1 = *(const float4*)(src + 4);
  float f[8] = {v0.x, v0.y, v0.z, v0.w, v1.x, v1.y, v1.z, v1.w};
  s16x8 h, l;
#pragma unroll
  for (int j = 0; j < 8; ++j) {
    ushort hb = f2bf(f[j]);
    float  r  = f[j] - bf2f(hb);
    h[j] = (short)hb;
    l[j] = (short)f2bf(r);
  }
  *hi = h; *lo = l;
}

// ---- prep: A = [x | h_prev] -> Ahi/Alo [16384][2048], k-group swizzled ----
// global layout: A[b][k ^ (((b>>1)&3)<<3)]  (zero-bank-conflict pair with uo
// read swizzle, measured SQ_LDS_BANK_CONFLICT=0 in round 1)
__global__ void prep_A(const float* __restrict__ x, const float* __restrict__ hp,
                       ushort* __restrict__ Ahi, ushort* __restrict__ Alo) {
  size_t i8 = ((size_t)blockIdx.x * 256 + threadIdx.x) * 8;
  int b = (int)(i8 >> 11);
  int k = (int)(i8 & 2047);
  const float* src = (k < 1024) ? (x + (size_t)b * 1024 + k)
                                : (hp + (size_t)b * 1024 + (k - 1024));
  s16x8 h, l;
  split8(src, &h, &l);
  int swz = (b >> 1) & 3;
  size_t dst = (size_t)b * KK + (size_t)(k ^ (swz << 3));
  *(s16x8*)(Ahi + dst) = h;
  *(s16x8*)(Alo + dst) = l;
}

// ---- prep: W gate-interleaved Wp[n][k], n = 4*h + g, same swizzle ----
__global__ void prep_W(const float* __restrict__ Wf, const float* __restrict__ Wi,
                       const float* __restrict__ Wg, const float* __restrict__ Wo,
                       const float* __restrict__ bf_, const float* __restrict__ bi_,
                       const float* __restrict__ bg_, const float* __restrict__ bo_,
                       ushort* __restrict__ Whi, ushort* __restrict__ Wlo,
                       float* __restrict__ bpack) {
  size_t i8 = ((size_t)blockIdx.x * 256 + threadIdx.x) * 8;
  int n = (int)(i8 >> 11);
  int k = (int)(i8 & 2047);
  int g = n & 3, h = n >> 2;
  const float* w = (g == 0) ? Wf : (g == 1) ? Wi : (g == 2) ? Wg : Wo;
  s16x8 hi, lo;
  split8(w + (size_t)h * KK + k, &hi, &lo);
  int swz = (n >> 1) & 3;
  size_t dst = (size_t)n * KK + (size_t)(k ^ (swz << 3));
  *(s16x8*)(Whi + dst) = hi;
  *(s16x8*)(Wlo + dst) = lo;
  if (k == 0) {
    const float* bb = (g == 0) ? bf_ : (g == 1) ? bi_ : (g == 2) ? bg_ : bo_;
    bpack[n] = bb[h];
  }
}

__device__ __forceinline__ void gl2lds16(const ushort* g, ushort* l) {
  auto gp = reinterpret_cast<const __attribute__((address_space(1))) uint32_t*>(
      reinterpret_cast<uintptr_t>(g));
  auto lp = reinterpret_cast<__attribute__((address_space(3))) uint32_t*>(
      reinterpret_cast<uintptr_t>(l));
  __builtin_amdgcn_global_load_lds(gp, lp, 16, 0, 0);
}

// one K=32 step: 2 phases, each {ds_read frags; stage issue; barrier;
// setprio(1); 16 MFMA; setprio(0)}; end-of-step wait handled by caller.
#define LSTM_STEP(S_, STAGE_EN_)                                               \
  {                                                                            \
    const int cur_ = (S_) & 3;                                                 \
    const ushort* lA_ = &lds[cur_][0][0];                                      \
    const ushort* lB_ = &lds[cur_][1][0];                                      \
    s16x8 af_[4], bfv_[4];                                                     \
    _Pragma("unroll") for (int mi = 0; mi < 4; ++mi)                           \
        af_[mi] = *(const s16x8*)(lA_ + aoffL[mi]);                            \
    _Pragma("unroll") for (int ni = 0; ni < 4; ++ni)                           \
        bfv_[ni] = *(const s16x8*)(lB_ + boffL[ni]);                           \
    if (STAGE_EN_) STAGE_A((S_) + 3, ((S_) + 3) & 3);                          \
    __builtin_amdgcn_s_barrier();                                              \
    __builtin_amdgcn_s_setprio(1);                                             \
    _Pragma("unroll") for (int mi = 0; mi < 4; ++mi)                           \
      _Pragma("unroll") for (int ni = 0; ni < 4; ++ni)                         \
          acc[mi][ni] = __builtin_amdgcn_mfma_f32_16x16x32_bf16(               \
              __builtin_bit_cast(bf16x8, af_[mi]),                             \
              __builtin_bit_cast(bf16x8, bfv_[ni]), acc[mi][ni], 0, 0, 0);     \
    __builtin_amdgcn_s_setprio(0);                                             \
    __builtin_amdgcn_s_barrier();                                              \
    _Pragma("unroll") for (int mi = 0; mi < 4; ++mi)                           \
        af_[mi] = *(const s16x8*)(lA_ + aoffL[4 + mi]);                        \
    if (STAGE_EN_) STAGE_B((S_) + 3, ((S_) + 3) & 3);                          \
    __builtin_amdgcn_s_barrier();                                              \
    __builtin_amdgcn_s_setprio(1);                                             \
    _Pragma("unroll") for (int mi = 0; mi < 4; ++mi)                           \
      _Pragma("unroll") for (int ni = 0; ni < 4; ++ni)                         \
          acc[4 + mi][ni] = __builtin_amdgcn_mfma_f32_16x16x32_bf16(           \
              __builtin_bit_cast(bf16x8, af_[mi]),                             \
              __builtin_bit_cast(bf16x8, bfv_[ni]), acc[4 + mi][ni], 0, 0, 0); \
    __builtin_amdgcn_s_setprio(0);                                             \
  }

__global__ __launch_bounds__(512, 2) void lstm_gemm8(
    const ushort* __restrict__ Ahi, const ushort* __restrict__ Alo,
    const ushort* __restrict__ Whi, const ushort* __restrict__ Wlo,
    const float* __restrict__ bpack, const float* __restrict__ c_prev,
    float* __restrict__ out) {
  __shared__ ushort lds[4][2][8192];  // ring-4 x {A,B} x [256][32] = 128 KiB

  const int t = threadIdx.x;
  const int lane = t & 63;
  const int wave = t >> 6;   // 0..7
  const int wm = wave >> 2;  // M half (0..1), wave tile 128x64
  const int wn = wave & 3;   // N quarter (0..3)
  const int mbase = blockIdx.y * 256;
  const int nbase = blockIdx.x * 256;

  const int lr = lane & 15;
  const int uo = ((lane >> 4) ^ ((lane >> 1) & 3)) * 8;  // swizzled k-slot

  int aoffL[8], boffL[4];
#pragma unroll
  for (int mi = 0; mi < 8; ++mi) aoffL[mi] = (wm * 128 + mi * 16 + lr) * 32 + uo;
#pragma unroll
  for (int ni = 0; ni < 4; ++ni) boffL[ni] = (wn * 64 + ni * 16 + lr) * 32 + uo;

  // staging addresses: thread t covers row t>>2 (+128 for 2nd load), 16B slot t&3
  const size_t arow = (size_t)(mbase + (t >> 2)) * KK + (size_t)(t & 3) * 8;
  const size_t brow = (size_t)(nbase + (t >> 2)) * KK + (size_t)(t & 3) * 8;
  const int ldsStageOff = (t & ~63) * 8;  // + implicit lane*8 elems

  auto STAGE_A = [&](int sv, int r) {
    int ksl = sv * 32;
    int seg = ksl >> 11;          // 0:Ah 1:Al 2:Ah
    int kcol = ksl & 2047;
    const ushort* ap = (seg == 1) ? Alo : Ahi;
    gl2lds16(ap + arow + kcol,            &lds[r][0][ldsStageOff]);
    gl2lds16(ap + arow + 128 * KK + kcol, &lds[r][0][4096 + ldsStageOff]);
  };
  auto STAGE_B = [&](int sv, int r) {
    int ksl = sv * 32;
    int seg = ksl >> 11;          // 0:Wh 1:Wh 2:Wl
    int kcol = ksl & 2047;
    const ushort* bp = (seg == 2) ? Wlo : Whi;
    gl2lds16(bp + brow + kcol,            &lds[r][1][ldsStageOff]);
    gl2lds16(bp + brow + 128 * KK + kcol, &lds[r][1][4096 + ldsStageOff]);
  };

  f32x4 acc[8][4];
#pragma unroll
  for (int mi = 0; mi < 8; ++mi)
#pragma unroll
    for (int ni = 0; ni < 4; ++ni) acc[mi][ni] = f32x4{0.f, 0.f, 0.f, 0.f};

  // prologue: stage steps 0,1,2 (12 loads); wait oldest 4 (step 0)
  STAGE_A(0, 0); STAGE_B(0, 0);
  STAGE_A(1, 1); STAGE_B(1, 1);
  STAGE_A(2, 2); STAGE_B(2, 2);
  asm volatile("s_waitcnt vmcnt(8)" ::: "memory");
  __builtin_amdgcn_s_barrier();

  // steady state: stage s+3 while computing s; vmcnt(8) = last 2 steps in flight
  for (int s = 0; s < KSTEPS - 3; ++s) {
    LSTM_STEP(s, 1);
    asm volatile("s_waitcnt vmcnt(8)" ::: "memory");
    __builtin_amdgcn_s_barrier();
  }
  // tail: drain once, then 3 staging-free steps
  asm volatile("s_waitcnt vmcnt(0)" ::: "memory");
  __builtin_amdgcn_s_barrier();
  for (int s = KSTEPS - 3; s < KSTEPS; ++s) {
    LSTM_STEP(s, 0);
    __builtin_amdgcn_s_barrier();
  }

  // epilogue: C/D layout col=lane&15 (n), row=(lane>>4)*4+reg (m)
  const int g = lr & 3;
#pragma unroll
  for (int mi = 0; mi < 8; ++mi) {
    const int m0 = mbase + wm * 128 + mi * 16 + (lane >> 4) * 4;
#pragma unroll
    for (int ni = 0; ni < 4; ++ni) {
      const int n_g = nbase + wn * 64 + ni * 16 + lr;
      const float bias = bpack[n_g];
      const int h = n_g >> 2;
#pragma unroll
      for (int r = 0; r < 4; ++r) {
        float v = acc[mi][ni][r] + bias;
        float t1 = __shfl_xor(v, 1, 64);
        float t2 = __shfl_xor(v, 2, 64);
        float t3 = __shfl_xor(v, 3, 64);
        float fv = (g == 0) ? v : (g == 1) ? t1 : (g == 2) ? t2 : t3;
        float iv = (g == 1) ? v : (g == 0) ? t1 : (g == 3) ? t2 : t3;
        float gv = (g == 2) ? v : (g == 3) ? t1 : (g == 0) ? t2 : t3;
        float ov = (g == 3) ? v : (g == 2) ? t1 : (g == 1) ? t2 : t3;
        int m = m0 + r;
        float cp = c_prev[(size_t)m * HH + h];
        float ft = 1.f / (1.f + __expf(-fv));
        float it = 1.f / (1.f + __expf(-iv));
        float gt = tanhf(gv);
        float ot = 1.f / (1.f + __expf(-ov));
        float cn = ft * cp + it * gt;
        float hn = ot * tanhf(cn);
        if (g == 0)      out[(size_t)m * HH + h] = hn;
        else if (g == 1) out[(size_t)BB * HH + (size_t)m * HH + h] = cn;
      }
    }
  }
}

// ---- fallback: naive fp32 (only if ws too small) ----
__global__ void lstm_naive(const float* __restrict__ x, const float* __restrict__ hp,
                           const float* __restrict__ cp,
                           const float* __restrict__ Wf, const float* __restrict__ bf_,
                           const float* __restrict__ Wi, const float* __restrict__ bi_,
                           const float* __restrict__ Wg, const float* __restrict__ bg_,
                           const float* __restrict__ Wo, const float* __restrict__ bo_,
                           float* __restrict__ out) {
  size_t idx = (size_t)blockIdx.x * 256 + threadIdx.x;
  int b = (int)(idx >> 10), h = (int)(idx & 1023);
  float sf = bf_[h], si = bi_[h], sg = bg_[h], so = bo_[h];
  const float* xr = x + (size_t)b * 1024;
  const float* hr = hp + (size_t)b * 1024;
  const float* wf = Wf + (size_t)h * KK;
  const float* wi = Wi + (size_t)h * KK;
  const float* wg = Wg + (size_t)h * KK;
  const float* wo = Wo + (size_t)h * KK;
  for (int k = 0; k < 1024; ++k) {
    float a = xr[k];
    sf += a * wf[k]; si += a * wi[k]; sg += a * wg[k]; so += a * wo[k];
  }
  for (int k = 0; k < 1024; ++k) {
    float a = hr[k];
    sf += a * wf[1024 + k]; si += a * wi[1024 + k];
    sg += a * wg[1024 + k]; so += a * wo[1024 + k];
  }
  float ft = 1.f / (1.f + expf(-sf));
  float it = 1.f / (1.f + expf(-si));
  float gt = tanhf(sg);
  float ot = 1.f / (1.f + expf(-so));
  float cn = ft * cp[idx] + it * gt;
  out[idx] = ot * tanhf(cn);
  out[(size_t)BB * HH + idx] = cn;
}

extern "C" void kernel_launch(void* const* d_in, const int* in_sizes, int n_in,
                              void* d_out, int out_size, void* d_ws, size_t ws_size,
                              hipStream_t stream) {
  const float* x  = (const float*)d_in[0];
  const float* hp = (const float*)d_in[1];
  const float* cp = (const float*)d_in[2];
  const float* Wf = (const float*)d_in[3];  const float* bf_ = (const float*)d_in[4];
  const float* Wi = (const float*)d_in[5];  const float* bi_ = (const float*)d_in[6];
  const float* Wg = (const float*)d_in[7];  const float* bg_ = (const float*)d_in[8];
  const float* Wo = (const float*)d_in[9];  const float* bo_ = (const float*)d_in[10];
  float* out = (float*)d_out;

  const size_t offAhi = 0;
  const size_t offAlo = (size_t)BB * KK * 2;              // 64 MiB
  const size_t offWhi = offAlo + (size_t)BB * KK * 2;     // 128 MiB
  const size_t offWlo = offWhi + (size_t)NN * KK * 2;     // 144 MiB
  const size_t offBp  = offWlo + (size_t)NN * KK * 2;     // 160 MiB
  const size_t needed = offBp + (size_t)NN * 4;

  if (ws_size < needed) {
    lstm_naive<<<(BB * HH) / 256, 256, 0, stream>>>(x, hp, cp, Wf, bf_, Wi, bi_, Wg, bg_, Wo, bo_, out);
    return;
  }

  ushort* Ahi = (ushort*)((char*)d_ws + offAhi);
  ushort* Alo = (ushort*)((char*)d_ws + offAlo);
  ushort* WhiP = (ushort*)((char*)d_ws + offWhi);
  ushort* WloP = (ushort*)((char*)d_ws + offWlo);
  float*  bpack = (float*)((char*)d_ws + offBp);

  prep_A<<<(BB * KK / 8) / 256, 256, 0, stream>>>(x, hp, Ahi, Alo);
  prep_W<<<(NN * KK / 8) / 256, 256, 0, stream>>>(Wf, Wi, Wg, Wo, bf_, bi_, bg_, bo_, WhiP, WloP, bpack);
  lstm_gemm8<<<dim3(NN / 256, BB / 256), 512, 0, stream>>>(Ahi, Alo, WhiP, WloP, bpack, cp, out);
}